// Round 12
// baseline (351.280 us; speedup 1.0000x reference)
//
#include <hip/hip_runtime.h>
#include <hip/hip_cooperative_groups.h>

namespace cg = cooperative_groups;

#define NEG_SLOPE 0.01f
typedef unsigned short ushort_t;

#define BSHIFT 9          // 512 nodes per dst-bucket
#define BSZ 512
#define SRCMASK 0x7FFFFFu // low 23 bits = src, high 9 bits = dst-local

typedef __attribute__((ext_vector_type(8))) short short8;
typedef __attribute__((ext_vector_type(4))) float f32x4;

static __device__ __forceinline__ float bf2f(ushort_t u) {
    return __uint_as_float(((unsigned int)u) << 16);
}
static __device__ __forceinline__ ushort_t f2bf(float f) {
    unsigned int x = __float_as_uint(f);
    x += 0x7fffu + ((x >> 16) & 1u);   // round-to-nearest-even
    return (ushort_t)(x >> 16);
}

// ---------------------------------------------------------------------------
// cooperative prep: P0 hist (per-chunk, LDS) + W-pack + sentinel
//                   P1 scan of m (block 0)
//                   P2 reorder into bucket-grouped ebuf
//                   P3 per-bucket degree/dinv/rowinfo + CSR fill (LDS cursors)
// grid = nbk blocks x 1024; chunk b == bucket b.
// ---------------------------------------------------------------------------
__global__ __launch_bounds__(1024) void prep_kernel(
        const int* __restrict__ src, const int* __restrict__ dst,
        int* __restrict__ m, unsigned* __restrict__ ebuf,
        int2* __restrict__ rowinfo, float* __restrict__ dinv,
        int* __restrict__ csr, int* __restrict__ galloc,
        ushort_t* __restrict__ xws, const float* __restrict__ W,
        ushort_t* __restrict__ wfrag,
        int e, int nbk, int chunk2, int n, int L) {
    cg::grid_group grid = cg::this_grid();
    __shared__ int sh[1537];
    int t = threadIdx.x, b = blockIdx.x;
    int nch = nbk;

    // ---- P0: histogram of chunk b (LDS only) ----
    if (t < 256) sh[t] = 0;
    __syncthreads();
    int base = b * chunk2;
    int lim  = e - base; if (lim > chunk2) lim = chunk2; if (lim < 0) lim = 0;
    for (int j = t; j < lim; j += 1024)
        atomicAdd(&sh[dst[base + j] >> BSHIFT], 1);
    // side jobs (no LDS use): W-pack on blocks 0..L-1, sentinel/galloc on block 0
    if (b < L && t >= 512 && t < 768) {
        int tt = t - 512;
        int lane = tt & 63, lg = lane >> 4, li = lane & 15;
        const float* Wl = W + (size_t)b * 4096;
        ushort_t* outp  = wfrag + (size_t)b * 4096;
        #pragma unroll
        for (int ff = 0; ff < 2; ++ff) {
            int f8 = (tt >> 6) * 2 + ff;
            int cgx = f8 >> 1, f = f8 & 1;
            #pragma unroll
            for (int ee = 0; ee < 8; ++ee)
                outp[(f8 * 64 + lane) * 8 + ee] =
                    f2bf(Wl[(lg * 8 + ee + 32 * f) * 64 + cgx * 16 + li]);
        }
    }
    if (b == 0 && t >= 768 && t < 832) xws[(size_t)n * 64 + (t - 768)] = 0;
    if (b == 0 && t == 1023) *galloc = 0;
    __syncthreads();
    if (t < nbk) m[t * nch + b] = sh[t];   // bucket-major

    grid.sync();

    // ---- P1: block 0 exclusive-scans m[0..M) (two-pass, no big local array) ----
    int M = nbk * nch;
    if (b == 0) {
        int per  = (M + 1023) >> 10;
        int idx0 = t * per;
        int sum = 0;
        for (int j = 0; j < per; ++j) {
            int idx = idx0 + j;
            if (idx < M) sum += m[idx];
        }
        sh[t] = sum;
        __syncthreads();
        for (int st = 1; st < 1024; st <<= 1) {
            int x = (t >= st) ? sh[t - st] : 0;
            __syncthreads();
            sh[t] += x;
            __syncthreads();
        }
        int run = (t == 0) ? 0 : sh[t - 1];
        for (int j = 0; j < per; ++j) {
            int idx = idx0 + j;
            if (idx < M) { int v = m[idx]; m[idx] = run; run += v; }
        }
    }

    grid.sync();

    // ---- P2: reorder chunk b into ebuf ----
    if (t < nbk) sh[t] = m[t * nch + b];
    __syncthreads();
    for (int j = t; j < lim; j += 1024) {
        int i = base + j;
        int d = dst[i];
        int pos = atomicAdd(&sh[d >> BSHIFT], 1);
        ebuf[pos] = (unsigned)src[i] | ((unsigned)(d & (BSZ - 1)) << 23);
    }

    grid.sync();

    // ---- P3: fillmerge bucket b ----
    int* lc   = sh;
    int* pref = sh + 512;
    int* cur  = sh + 1024;
    if (t < BSZ) lc[t] = 0;
    __syncthreads();
    int bs = m[b * nch];
    int be = (b + 1 < nbk) ? m[(b + 1) * nch] : e;
    for (int i = bs + t; i < be; i += 1024)
        atomicAdd(&lc[ebuf[i] >> 23], 1);
    __syncthreads();
    int v = (b << BSHIFT) + t;
    int deg = 0, pd = 0;
    if (t < BSZ && v < n) {
        deg = lc[t];
        pd  = (deg + 7) & ~7;
    }
    if (t < BSZ) pref[t] = pd;
    __syncthreads();
    for (int s = 1; s < BSZ; s <<= 1) {
        int x = (t < BSZ && t >= s) ? pref[t - s] : 0;
        __syncthreads();
        if (t < BSZ) pref[t] += x;
        __syncthreads();
    }
    if (t == 0) sh[1536] = atomicAdd(galloc, pref[BSZ - 1]);
    __syncthreads();
    int abase = sh[1536];
    int start = 0;
    if (t < BSZ) {
        start  = abase + pref[t] - pd;
        cur[t] = start;
        if (v < n) {
            rowinfo[v] = make_int2(start, pd);
            dinv[v]    = rsqrtf((float)deg + 1.0f);
        }
    }
    __syncthreads();
    for (int i = bs + t; i < be; i += 1024) {
        unsigned ev = ebuf[i];
        int slot = atomicAdd(&cur[ev >> 23], 1);
        csr[slot] = (int)(ev & SRCMASK);
    }
    __syncthreads();
    if (t < BSZ && v < n) {
        int endp = start + pd;
        for (int s2 = cur[t]; s2 < endp; ++s2) csr[s2] = n;   // pad sentinels
    }
}

// ---------------------------------------------------------------------------
// MFMA gemm: xws = (Xin @ W) * dinv[row], bf16 out. (unchanged from r11)
// ---------------------------------------------------------------------------
template<int XF32>
__global__ __launch_bounds__(256) void gemm_mfma(const float* __restrict__ Xf,
                                                 const ushort_t* __restrict__ Xh,
                                                 const ushort_t* __restrict__ wfrag,
                                                 const float* __restrict__ dinv,
                                                 ushort_t* __restrict__ xws, int n) {
    int lane = threadIdx.x & 63;
    int wv   = threadIdx.x >> 6;
    int lg   = lane >> 4;
    int li   = lane & 15;

    short8 bfr[8];
    const short8* wp = (const short8*)wfrag;
    #pragma unroll
    for (int f8 = 0; f8 < 8; ++f8) bfr[f8] = wp[f8 * 64 + lane];

    int row0 = (blockIdx.x * 4 + wv) * 64;

    #pragma unroll 1
    for (int it = 0; it < 4; ++it) {
        int rbase = row0 + it * 16;
        if (rbase >= n) break;
        int r = rbase + li;

        short8 afr[2];
        if (XF32) {
            #pragma unroll
            for (int f = 0; f < 2; ++f) {
                const float* p = Xf + (size_t)r * 64 + lg * 8 + 32 * f;
                float4 c0 = *(const float4*)(p);
                float4 c1 = *(const float4*)(p + 4);
                short8 a;
                a[0] = (short)f2bf(c0.x); a[1] = (short)f2bf(c0.y);
                a[2] = (short)f2bf(c0.z); a[3] = (short)f2bf(c0.w);
                a[4] = (short)f2bf(c1.x); a[5] = (short)f2bf(c1.y);
                a[6] = (short)f2bf(c1.z); a[7] = (short)f2bf(c1.w);
                afr[f] = a;
            }
        } else {
            const ushort_t* p = Xh + (size_t)r * 64 + lg * 8;
            afr[0] = *(const short8*)(p);
            afr[1] = *(const short8*)(p + 32);
        }

        float dv[4];
        #pragma unroll
        for (int reg = 0; reg < 4; ++reg) dv[reg] = dinv[rbase + lg * 4 + reg];

        #pragma unroll
        for (int cg2 = 0; cg2 < 4; ++cg2) {
            f32x4 acc = {0.f, 0.f, 0.f, 0.f};
            acc = __builtin_amdgcn_mfma_f32_16x16x32_bf16(afr[0], bfr[cg2 * 2 + 0], acc, 0, 0, 0);
            acc = __builtin_amdgcn_mfma_f32_16x16x32_bf16(afr[1], bfr[cg2 * 2 + 1], acc, 0, 0, 0);
            #pragma unroll
            for (int reg = 0; reg < 4; ++reg) {
                int rr = rbase + lg * 4 + reg;
                xws[(size_t)rr * 64 + cg2 * 16 + li] = f2bf(acc[reg] * dv[reg]);
            }
        }
    }
}

// ---------------------------------------------------------------------------
// pull aggregation (unchanged from r11): two nodes per wave, 8+8 interleave,
// register accumulation, leakyReLU + residual fused; FINAL fuses the
// weighted running-sum output.
// ---------------------------------------------------------------------------
template<int XF32, int FINAL>
__global__ __launch_bounds__(256) void agg_kernel(
        const ushort_t* __restrict__ xws,
        const int2* __restrict__ rowinfo,
        const int* __restrict__ csr,
        const float* __restrict__ dinv,
        const float* __restrict__ bias,
        const float* __restrict__ xinf,
        const ushort_t* __restrict__ xinh,
        ushort_t* __restrict__ xout,
        const float* __restrict__ Xres,
        const ushort_t* __restrict__ x1res,
        float* __restrict__ outf,
        int n) {
    int tid = threadIdx.x;
    int c   = tid & 63;
    int w   = blockIdx.x * 4 + (tid >> 6);
    int v0  = w * 2;
    if (v0 >= n) return;
    int  v1   = v0 + 1;
    bool has1 = (v1 < n);
    int  v1c  = has1 ? v1 : v0;

    int2 ri0 = rowinfo[v0];
    int2 ri1 = rowinfo[v1c];
    int b0 = ri0.x, len0 = ri0.y;
    int b1 = ri1.x, len1 = has1 ? ri1.y : 0;

    size_t vo0 = (size_t)v0  * 64 + c;
    size_t vo1 = (size_t)v1c * 64 + c;
    float acc0 = bf2f(xws[vo0]);
    float acc1 = bf2f(xws[vo1]);

    int mxlen = len0 > len1 ? len0 : len1;
    for (int off = 0; off < mxlen; off += 64) {
        int r0 = len0 - off;
        int r1 = len1 - off;
        int ce0 = (c < r0) ? csr[b0 + off + c] : n;
        int ce1 = (c < r1) ? csr[b1 + off + c] : n;
        int m0 = r0 < 64 ? r0 : 64;
        int m1 = r1 < 64 ? r1 : 64;
        int mx = m0 > m1 ? m0 : m1;
        for (int j0 = 0; j0 < mx; j0 += 8) {
            float g0[8], g1[8];
            bool p0 = j0 < m0, p1 = j0 < m1;
            if (p0) {
                #pragma unroll
                for (int j = 0; j < 8; ++j) {
                    int s = __builtin_amdgcn_readlane(ce0, j0 + j);
                    g0[j] = bf2f(xws[(size_t)(unsigned)s * 64 + c]);
                }
            }
            if (p1) {
                #pragma unroll
                for (int j = 0; j < 8; ++j) {
                    int s = __builtin_amdgcn_readlane(ce1, j0 + j);
                    g1[j] = bf2f(xws[(size_t)(unsigned)s * 64 + c]);
                }
            }
            if (p0) {
                #pragma unroll
                for (int j = 0; j < 8; ++j) acc0 += g0[j];
            }
            if (p1) {
                #pragma unroll
                for (int j = 0; j < 8; ++j) acc1 += g1[j];
            }
        }
    }

    {
        float dv0 = dinv[v0];
        float t0  = bias[c] + dv0 * acc0;
        float a0  = t0 >= 0.f ? t0 : NEG_SLOPE * t0;
        float xi0 = XF32 ? xinf[vo0] : bf2f(xinh[vo0]);
        float xn0 = a0 + xi0;
        if (FINAL) {
            outf[vo0] = Xres[vo0] + 0.5f * bf2f(x1res[vo0])
                        + (1.f / 3.f) * xi0 + 0.25f * xn0;
        } else {
            xout[vo0] = f2bf(xn0);
        }
    }
    if (has1) {
        float dv1 = dinv[v1];
        float t1  = bias[c] + dv1 * acc1;
        float a1  = t1 >= 0.f ? t1 : NEG_SLOPE * t1;
        float xi1 = XF32 ? xinf[vo1] : bf2f(xinh[vo1]);
        float xn1 = a1 + xi1;
        if (FINAL) {
            outf[vo1] = Xres[vo1] + 0.5f * bf2f(x1res[vo1])
                        + (1.f / 3.f) * xi1 + 0.25f * xn1;
        } else {
            xout[vo1] = f2bf(xn1);
        }
    }
}

extern "C" void kernel_launch(void* const* d_in, const int* in_sizes, int n_in,
                              void* d_out, int out_size, void* d_ws, size_t ws_size,
                              hipStream_t stream) {
    const float* X   = (const float*)d_in[0];
    const int*   adj = (const int*)d_in[1];
    const float* W   = (const float*)d_in[2];
    const float* b   = (const float*)d_in[3];
    float* out = (float*)d_out;

    const int nd = in_sizes[0];          // N * 64
    const int n  = nd >> 6;              // N
    const int e  = in_sizes[1] / 2;      // E
    const int L  = in_sizes[3] / 64;     // layers (3)

    const int* src = adj;
    const int* dstp = adj + e;

    const int nbk    = (n + BSZ - 1) >> BSHIFT;          // ~196
    const int chunk2 = (e + nbk - 1) / nbk;              // edges per chunk
    const int csr_len = e + 8 * n + 64;

    // workspace layout
    unsigned* ebuf   = (unsigned*)d_ws;                  // e u32
    int*      csr    = (int*)(ebuf + e);                 // csr_len
    int*      m      = csr + csr_len;                    // nbk*nbk (<= 65536)
    int*      galloc = m + 65536;                        // 4 (16B pad)
    ushort_t* wfrag  = (ushort_t*)(galloc + 4);          // 3 * 4096 bf16 (24KB)
    int2*     rowinfo= (int2*)(wfrag + 3 * 4096);        // n int2
    float*    dinv   = (float*)(rowinfo + n);            // n
    size_t    off    = ((size_t)(n + 3) & ~(size_t)3);
    ushort_t* xws    = (ushort_t*)(dinv + off);          // nd + 64
    ushort_t* x1     = xws + (size_t)nd + 64;            // nd
    ushort_t* x2     = x1  + (size_t)nd;                 // nd

    // ---- cooperative prep: hist + scan + reorder + fill in ONE launch ----
    {
        const int*  a_src = src;  const int* a_dst = dstp;
        int*        a_m = m;      unsigned* a_ebuf = ebuf;
        int2*       a_ri = rowinfo; float* a_dinv = dinv;
        int*        a_csr = csr;  int* a_gal = galloc;
        ushort_t*   a_xws = xws;  const float* a_W = W;
        ushort_t*   a_wf = wfrag;
        int a_e = e, a_nbk = nbk, a_ch = chunk2, a_n = n, a_L = L;
        void* args[] = { &a_src, &a_dst, &a_m, &a_ebuf, &a_ri, &a_dinv,
                         &a_csr, &a_gal, &a_xws, &a_W, &a_wf,
                         &a_e, &a_nbk, &a_ch, &a_n, &a_L };
        hipLaunchCooperativeKernel((void*)prep_kernel, dim3(nbk), dim3(1024),
                                   args, 0, stream);
    }

    // ---- layers ----
    int gemm_blocks = (n + 255) / 256;   // 4 waves x 64 rows per block
    int agg_blocks  = (n + 7) / 8;       // 2 nodes/wave, 4 waves/block
    // layer 0 (f32 X in, bf16 x1 out)
    gemm_mfma<1><<<gemm_blocks, 256, 0, stream>>>(X, nullptr, wfrag, dinv, xws, n);
    agg_kernel<1, 0><<<agg_blocks, 256, 0, stream>>>(xws, rowinfo, csr, dinv, b,
                                                     X, nullptr, x1,
                                                     nullptr, nullptr, nullptr, n);
    // layer 1
    gemm_mfma<0><<<gemm_blocks, 256, 0, stream>>>(nullptr, x1, wfrag + 4096, dinv, xws, n);
    agg_kernel<0, 0><<<agg_blocks, 256, 0, stream>>>(xws, rowinfo, csr, dinv, b + 64,
                                                     nullptr, x1, x2,
                                                     nullptr, nullptr, nullptr, n);
    // layer 2 (fused final: out = X + x1/2 + x2/3 + xn3/4)
    gemm_mfma<0><<<gemm_blocks, 256, 0, stream>>>(nullptr, x2, wfrag + 8192, dinv, xws, n);
    agg_kernel<0, 1><<<agg_blocks, 256, 0, stream>>>(xws, rowinfo, csr, dinv, b + 128,
                                                     nullptr, x2, nullptr,
                                                     X, x1, out, n);
}

// Round 13
// 250.012 us; speedup vs baseline: 1.4051x; 1.4051x over previous
//
#include <hip/hip_runtime.h>

#define NEG_SLOPE 0.01f
typedef unsigned short ushort_t;

#define CHUNK 8192        // edges per histogram/reorder block (153 blocks)
#define BSHIFT 9          // 512 nodes per dst-bucket
#define BSZ 512
#define SRCMASK 0x7FFFFFu // low 23 bits = src, high 9 bits = dst-local

typedef __attribute__((ext_vector_type(8))) short short8;
typedef __attribute__((ext_vector_type(4))) float f32x4;

static __device__ __forceinline__ float bf2f(ushort_t u) {
    return __uint_as_float(((unsigned int)u) << 16);
}
static __device__ __forceinline__ ushort_t f2bf(float f) {
    unsigned int x = __float_as_uint(f);
    x += 0x7fffu + ((x >> 16) & 1u);   // round-to-nearest-even
    return (ushort_t)(x >> 16);
}

// ---------------------------------------------------------------------------
// phase A: per-chunk dst-bucket histogram (LDS only) + zero xws sentinel row.
// Blocks >= nch instead pack W[layer] into MFMA B-fragment layout (bf16).
// ---------------------------------------------------------------------------
__global__ __launch_bounds__(1024) void hist_kernel(const int* __restrict__ dst,
                                                    int* __restrict__ m,
                                                    ushort_t* __restrict__ xws,
                                                    const float* __restrict__ W,
                                                    ushort_t* __restrict__ wfrag,
                                                    int e, int nbk, int nch, int n) {
    int t = threadIdx.x;
    if (blockIdx.x >= nch) {               // W-pack blocks (one per layer)
        int layer = blockIdx.x - nch;
        if (t < 256) {
            int lane = t & 63;
            int lg   = lane >> 4;
            int li   = lane & 15;
            const float* Wl = W + (size_t)layer * 4096;
            ushort_t* outp  = wfrag + (size_t)layer * 4096;
            #pragma unroll
            for (int ff = 0; ff < 2; ++ff) {
                int f8 = (t >> 6) * 2 + ff;
                int cg = f8 >> 1, f = f8 & 1;
                #pragma unroll
                for (int ee = 0; ee < 8; ++ee) {
                    int k   = lg * 8 + ee + 32 * f;
                    int col = cg * 16 + li;
                    outp[(f8 * 64 + lane) * 8 + ee] = f2bf(Wl[k * 64 + col]);
                }
            }
        }
        return;
    }
    __shared__ int lcnt[256];
    if (t < 256) lcnt[t] = 0;
    __syncthreads();
    int base = blockIdx.x * CHUNK;
    int lim  = e - base; if (lim > CHUNK) lim = CHUNK;
    for (int j = t; j < lim; j += 1024)
        atomicAdd(&lcnt[dst[base + j] >> BSHIFT], 1);
    __syncthreads();
    if (t < nbk) m[t * nch + blockIdx.x] = lcnt[t];   // bucket-major
    if (blockIdx.x == 0 && t < 64) xws[(size_t)n * 64 + t] = 0;  // sentinel row
}

// exclusive scan of m[0..M), two-pass range scan (handles M up to 1024*per);
// also zeroes the global allocator
__global__ __launch_bounds__(1024) void scanm_kernel(int* __restrict__ m, int M,
                                                     int* __restrict__ galloc) {
    __shared__ int ts[1024];
    int t = threadIdx.x;
    int per  = (M + 1023) >> 10;
    int idx0 = t * per;
    int sum = 0;
    for (int j = 0; j < per; ++j) {
        int idx = idx0 + j;
        if (idx < M) sum += m[idx];
    }
    ts[t] = sum;
    __syncthreads();
    for (int st = 1; st < 1024; st <<= 1) {
        int x = (t >= st) ? ts[t - st] : 0;
        __syncthreads();
        ts[t] += x;
        __syncthreads();
    }
    int run = (t == 0) ? 0 : ts[t - 1];
    for (int j = 0; j < per; ++j) {
        int idx = idx0 + j;
        if (idx < M) { int v = m[idx]; m[idx] = run; run += v; }
    }
    if (t == 0) *galloc = 0;
}

// phase B: reorder edges into bucket-grouped ebuf; packed u32 = src | dloc<<23
__global__ __launch_bounds__(1024) void reorder_kernel(const int* __restrict__ src,
                                                       const int* __restrict__ dst,
                                                       const int* __restrict__ m,
                                                       unsigned* __restrict__ ebuf,
                                                       int e, int nbk, int nch) {
    __shared__ int cur[256];
    int t = threadIdx.x;
    if (t < nbk) cur[t] = m[t * nch + blockIdx.x];
    __syncthreads();
    int base = blockIdx.x * CHUNK;
    int lim  = e - base; if (lim > CHUNK) lim = CHUNK;
    for (int j = t; j < lim; j += 1024) {
        int i = base + j;
        int d = dst[i];
        int pos = atomicAdd(&cur[d >> BSHIFT], 1);
        ebuf[pos] = (unsigned)src[i] | ((unsigned)(d & (BSZ - 1)) << 23);
    }
}

// ---------------------------------------------------------------------------
// phase C (merged): per-bucket degree count -> dinv + rowinfo(start,plen),
// CSR space via one global atomic per block, fill CSR with LDS cursors,
// pad with sentinel n. One block per bucket; all csr writes L2-local.
// ---------------------------------------------------------------------------
__global__ __launch_bounds__(1024) void fillmerge_kernel(const unsigned* __restrict__ ebuf,
                                                         const int* __restrict__ m,
                                                         int* __restrict__ galloc,
                                                         int2* __restrict__ rowinfo,
                                                         float* __restrict__ dinv,
                                                         int* __restrict__ csr,
                                                         int e, int nbk, int nch, int n) {
    __shared__ int lc[BSZ];
    __shared__ int pref[BSZ];
    __shared__ int cur[BSZ];
    __shared__ int basesh;
    int t = threadIdx.x;
    int b = blockIdx.x;
    if (t < BSZ) lc[t] = 0;
    __syncthreads();
    int bs = m[b * nch];
    int be = (b + 1 < nbk) ? m[(b + 1) * nch] : e;
    for (int i = bs + t; i < be; i += 1024)
        atomicAdd(&lc[ebuf[i] >> 23], 1);
    __syncthreads();
    int v = (b << BSHIFT) + t;
    int deg = 0, pd = 0;
    if (t < BSZ && v < n) {
        deg = lc[t];
        pd  = (deg + 7) & ~7;
    }
    if (t < BSZ) pref[t] = pd;
    __syncthreads();
    for (int s = 1; s < BSZ; s <<= 1) {
        int x = (t < BSZ && t >= s) ? pref[t - s] : 0;
        __syncthreads();
        if (t < BSZ) pref[t] += x;
        __syncthreads();
    }
    if (t == 0) basesh = atomicAdd(galloc, pref[BSZ - 1]);
    __syncthreads();
    int base = basesh;
    int start = 0;
    if (t < BSZ) {
        start  = base + pref[t] - pd;
        cur[t] = start;
        if (v < n) {
            rowinfo[v] = make_int2(start, pd);
            dinv[v]    = rsqrtf((float)deg + 1.0f);
        }
    }
    __syncthreads();
    for (int i = bs + t; i < be; i += 1024) {
        unsigned ev = ebuf[i];
        int slot = atomicAdd(&cur[ev >> 23], 1);
        csr[slot] = (int)(ev & SRCMASK);
    }
    __syncthreads();
    if (t < BSZ && v < n) {
        int endp = start + pd;
        for (int s2 = cur[t]; s2 < endp; ++s2) csr[s2] = n;   // pad sentinels
    }
}

// ---------------------------------------------------------------------------
// MFMA gemm: xws = (Xin @ W) * dinv[row], bf16 out.
// Per wave: 64 rows (4 slabs of 16), 8 B-frags held in VGPRs, 8 MFMA/slab.
// A/B packed with the same k-bijection (lg*8+e+32f) -> sum over k is exact.
// C/D layout (verified m89): col = lane&15, row = (lane>>4)*4 + reg.
// ---------------------------------------------------------------------------
template<int XF32>
__global__ __launch_bounds__(256) void gemm_mfma(const float* __restrict__ Xf,
                                                 const ushort_t* __restrict__ Xh,
                                                 const ushort_t* __restrict__ wfrag,
                                                 const float* __restrict__ dinv,
                                                 ushort_t* __restrict__ xws, int n) {
    int lane = threadIdx.x & 63;
    int wv   = threadIdx.x >> 6;
    int lg   = lane >> 4;
    int li   = lane & 15;

    short8 bfr[8];
    const short8* wp = (const short8*)wfrag;
    #pragma unroll
    for (int f8 = 0; f8 < 8; ++f8) bfr[f8] = wp[f8 * 64 + lane];

    int row0 = (blockIdx.x * 4 + wv) * 64;

    #pragma unroll 1
    for (int it = 0; it < 4; ++it) {
        int rbase = row0 + it * 16;
        if (rbase >= n) break;
        int r = rbase + li;

        short8 afr[2];
        if (XF32) {
            #pragma unroll
            for (int f = 0; f < 2; ++f) {
                const float* p = Xf + (size_t)r * 64 + lg * 8 + 32 * f;
                float4 c0 = *(const float4*)(p);
                float4 c1 = *(const float4*)(p + 4);
                short8 a;
                a[0] = (short)f2bf(c0.x); a[1] = (short)f2bf(c0.y);
                a[2] = (short)f2bf(c0.z); a[3] = (short)f2bf(c0.w);
                a[4] = (short)f2bf(c1.x); a[5] = (short)f2bf(c1.y);
                a[6] = (short)f2bf(c1.z); a[7] = (short)f2bf(c1.w);
                afr[f] = a;
            }
        } else {
            const ushort_t* p = Xh + (size_t)r * 64 + lg * 8;
            afr[0] = *(const short8*)(p);
            afr[1] = *(const short8*)(p + 32);
        }

        float dv[4];
        #pragma unroll
        for (int reg = 0; reg < 4; ++reg) dv[reg] = dinv[rbase + lg * 4 + reg];

        #pragma unroll
        for (int cg = 0; cg < 4; ++cg) {
            f32x4 acc = {0.f, 0.f, 0.f, 0.f};
            acc = __builtin_amdgcn_mfma_f32_16x16x32_bf16(afr[0], bfr[cg * 2 + 0], acc, 0, 0, 0);
            acc = __builtin_amdgcn_mfma_f32_16x16x32_bf16(afr[1], bfr[cg * 2 + 1], acc, 0, 0, 0);
            #pragma unroll
            for (int reg = 0; reg < 4; ++reg) {
                int rr = rbase + lg * 4 + reg;
                xws[(size_t)rr * 64 + cg * 16 + li] = f2bf(acc[reg] * dv[reg]);
            }
        }
    }
}

// ---------------------------------------------------------------------------
// pull aggregation: TWO nodes per wave, interleaved 8+8 gather groups,
// register accumulation, leakyReLU + residual fused.
// FINAL=1 (last layer): also computes out = X + x1/2 + x2/3 + xn3/4 (f32)
// and skips the bf16 x3 write entirely.
// ---------------------------------------------------------------------------
template<int XF32, int FINAL>
__global__ __launch_bounds__(256) void agg_kernel(
        const ushort_t* __restrict__ xws,
        const int2* __restrict__ rowinfo,
        const int* __restrict__ csr,
        const float* __restrict__ dinv,
        const float* __restrict__ bias,
        const float* __restrict__ xinf,    // f32 input (layer 0)
        const ushort_t* __restrict__ xinh, // bf16 input (layers >0)
        ushort_t* __restrict__ xout,       // bf16 layer output (FINAL=0)
        const float* __restrict__ Xres,    // X (FINAL=1)
        const ushort_t* __restrict__ x1res,// x1 (FINAL=1)
        float* __restrict__ outf,          // final f32 out (FINAL=1)
        int n) {
    int tid = threadIdx.x;
    int c   = tid & 63;
    int w   = blockIdx.x * 4 + (tid >> 6);
    int v0  = w * 2;
    if (v0 >= n) return;
    int  v1   = v0 + 1;
    bool has1 = (v1 < n);
    int  v1c  = has1 ? v1 : v0;

    int2 ri0 = rowinfo[v0];
    int2 ri1 = rowinfo[v1c];
    int b0 = ri0.x, len0 = ri0.y;
    int b1 = ri1.x, len1 = has1 ? ri1.y : 0;

    size_t vo0 = (size_t)v0  * 64 + c;
    size_t vo1 = (size_t)v1c * 64 + c;
    float acc0 = bf2f(xws[vo0]);     // self term (pre-scaled by dinv)
    float acc1 = bf2f(xws[vo1]);

    int mxlen = len0 > len1 ? len0 : len1;
    for (int off = 0; off < mxlen; off += 64) {
        int r0 = len0 - off;
        int r1 = len1 - off;
        int ce0 = (c < r0) ? csr[b0 + off + c] : n;
        int ce1 = (c < r1) ? csr[b1 + off + c] : n;
        int m0 = r0 < 64 ? r0 : 64;           // multiple of 8 (or <=0)
        int m1 = r1 < 64 ? r1 : 64;
        int mx = m0 > m1 ? m0 : m1;
        for (int j0 = 0; j0 < mx; j0 += 8) {
            float g0[8], g1[8];
            bool p0 = j0 < m0, p1 = j0 < m1;
            if (p0) {
                #pragma unroll
                for (int j = 0; j < 8; ++j) {
                    int s = __builtin_amdgcn_readlane(ce0, j0 + j);
                    g0[j] = bf2f(xws[(size_t)(unsigned)s * 64 + c]);
                }
            }
            if (p1) {
                #pragma unroll
                for (int j = 0; j < 8; ++j) {
                    int s = __builtin_amdgcn_readlane(ce1, j0 + j);
                    g1[j] = bf2f(xws[(size_t)(unsigned)s * 64 + c]);
                }
            }
            if (p0) {
                #pragma unroll
                for (int j = 0; j < 8; ++j) acc0 += g0[j];
            }
            if (p1) {
                #pragma unroll
                for (int j = 0; j < 8; ++j) acc1 += g1[j];
            }
        }
    }

    {
        float dv0 = dinv[v0];
        float t0  = bias[c] + dv0 * acc0;
        float a0  = t0 >= 0.f ? t0 : NEG_SLOPE * t0;
        float xi0 = XF32 ? xinf[vo0] : bf2f(xinh[vo0]);
        float xn0 = a0 + xi0;
        if (FINAL) {
            outf[vo0] = Xres[vo0] + 0.5f * bf2f(x1res[vo0])
                        + (1.f / 3.f) * xi0 + 0.25f * xn0;
        } else {
            xout[vo0] = f2bf(xn0);
        }
    }
    if (has1) {
        float dv1 = dinv[v1];
        float t1  = bias[c] + dv1 * acc1;
        float a1  = t1 >= 0.f ? t1 : NEG_SLOPE * t1;
        float xi1 = XF32 ? xinf[vo1] : bf2f(xinh[vo1]);
        float xn1 = a1 + xi1;
        if (FINAL) {
            outf[vo1] = Xres[vo1] + 0.5f * bf2f(x1res[vo1])
                        + (1.f / 3.f) * xi1 + 0.25f * xn1;
        } else {
            xout[vo1] = f2bf(xn1);
        }
    }
}

extern "C" void kernel_launch(void* const* d_in, const int* in_sizes, int n_in,
                              void* d_out, int out_size, void* d_ws, size_t ws_size,
                              hipStream_t stream) {
    const float* X   = (const float*)d_in[0];
    const int*   adj = (const int*)d_in[1];
    const float* W   = (const float*)d_in[2];
    const float* b   = (const float*)d_in[3];
    float* out = (float*)d_out;

    const int nd = in_sizes[0];          // N * 64
    const int n  = nd >> 6;              // N
    const int e  = in_sizes[1] / 2;      // E
    const int L  = in_sizes[3] / 64;     // layers (3)

    const int* src = adj;
    const int* dst = adj + e;

    const int nbk = (n + BSZ - 1) >> BSHIFT;             // ~196
    const int nch = (e + CHUNK - 1) / CHUNK;             // ~153
    const int M   = nbk * nch;                           // ~30K (<= 65536)
    const int csr_len = e + 8 * n + 64;

    // workspace layout
    unsigned* ebuf   = (unsigned*)d_ws;                  // e u32
    int*      csr    = (int*)(ebuf + e);                 // csr_len
    int*      m      = csr + csr_len;                    // 65536
    int*      galloc = m + 65536;                        // 4 (16B pad)
    ushort_t* wfrag  = (ushort_t*)(galloc + 4);          // 3 * 4096 bf16 (24KB)
    int2*     rowinfo= (int2*)(wfrag + 3 * 4096);        // n int2
    float*    dinv   = (float*)(rowinfo + n);            // n
    size_t    off    = ((size_t)(n + 3) & ~(size_t)3);
    ushort_t* xws    = (ushort_t*)(dinv + off);          // nd + 64
    ushort_t* x1     = xws + (size_t)nd + 64;            // nd
    ushort_t* x2     = x1  + (size_t)nd;                 // nd

    // ---- preprocessing (W-pack folded into hist's tail blocks) ----
    hist_kernel<<<nch + L, 1024, 0, stream>>>(dst, m, xws, W, wfrag, e, nbk, nch, n);
    scanm_kernel<<<1, 1024, 0, stream>>>(m, M, galloc);
    reorder_kernel<<<nch, 1024, 0, stream>>>(src, dst, m, ebuf, e, nbk, nch);
    fillmerge_kernel<<<nbk, 1024, 0, stream>>>(ebuf, m, galloc, rowinfo, dinv,
                                               csr, e, nbk, nch, n);

    // ---- layers ----
    int gemm_blocks = (n + 255) / 256;   // 4 waves x 64 rows per block
    int agg_blocks  = (n + 7) / 8;       // 2 nodes/wave, 4 waves/block
    // layer 0 (f32 X in, bf16 x1 out)
    gemm_mfma<1><<<gemm_blocks, 256, 0, stream>>>(X, nullptr, wfrag, dinv, xws, n);
    agg_kernel<1, 0><<<agg_blocks, 256, 0, stream>>>(xws, rowinfo, csr, dinv, b,
                                                     X, nullptr, x1,
                                                     nullptr, nullptr, nullptr, n);
    // layer 1
    gemm_mfma<0><<<gemm_blocks, 256, 0, stream>>>(nullptr, x1, wfrag + 4096, dinv, xws, n);
    agg_kernel<0, 0><<<agg_blocks, 256, 0, stream>>>(xws, rowinfo, csr, dinv, b + 64,
                                                     nullptr, x1, x2,
                                                     nullptr, nullptr, nullptr, n);
    // layer 2 (fused final: out = X + x1/2 + x2/3 + xn3/4)
    gemm_mfma<0><<<gemm_blocks, 256, 0, stream>>>(nullptr, x2, wfrag + 8192, dinv, xws, n);
    agg_kernel<0, 1><<<agg_blocks, 256, 0, stream>>>(xws, rowinfo, csr, dinv, b + 128,
                                                     nullptr, x2, nullptr,
                                                     X, x1, out, n);
}

// Round 14
// 218.322 us; speedup vs baseline: 1.6090x; 1.1452x over previous
//
#include <hip/hip_runtime.h>

#define NEG_SLOPE 0.01f
typedef unsigned short ushort_t;

#define CHUNK 16384       // edges per reorder block (r11-proven)
#define BSHIFT 9          // 512 nodes per dst-bucket
#define BSZ 512
#define SRCMASK 0x7FFFFFu // low 23 bits = src, high 9 bits = dst-local

typedef __attribute__((ext_vector_type(8))) short short8;
typedef __attribute__((ext_vector_type(4))) float f32x4;

static __device__ __forceinline__ float bf2f(ushort_t u) {
    return __uint_as_float(((unsigned int)u) << 16);
}
static __device__ __forceinline__ ushort_t f2bf(float f) {
    unsigned int x = __float_as_uint(f);
    x += 0x7fffu + ((x >> 16) & 1u);   // round-to-nearest-even
    return (ushort_t)(x >> 16);
}

// ---------------------------------------------------------------------------
// merged hist+alloc+reorder: per-chunk LDS histogram -> one global atomicAdd
// per touched bucket claims a segment in that bucket's fixed-cap region ->
// scatter packed edges (src | dloc<<23). Tail blocks (>= nch) pack W into
// MFMA B-fragment layout; block 0 zeroes the xws sentinel row.
// ---------------------------------------------------------------------------
__global__ __launch_bounds__(1024) void reorder2_kernel(
        const int* __restrict__ src, const int* __restrict__ dst,
        int* __restrict__ gcur, unsigned* __restrict__ ebuf,
        const float* __restrict__ W, ushort_t* __restrict__ wfrag,
        ushort_t* __restrict__ xws,
        int e, int nbk, int nch, int cap, int n, int L) {
    int t = threadIdx.x;
    if (blockIdx.x >= nch) {               // W-pack blocks (one per layer)
        int layer = blockIdx.x - nch;
        if (t < 256) {
            int lane = t & 63;
            int lg   = lane >> 4;
            int li   = lane & 15;
            const float* Wl = W + (size_t)layer * 4096;
            ushort_t* outp  = wfrag + (size_t)layer * 4096;
            #pragma unroll
            for (int ff = 0; ff < 2; ++ff) {
                int f8 = (t >> 6) * 2 + ff;
                int cg = f8 >> 1, f = f8 & 1;
                #pragma unroll
                for (int ee = 0; ee < 8; ++ee) {
                    int k   = lg * 8 + ee + 32 * f;
                    int col = cg * 16 + li;
                    outp[(f8 * 64 + lane) * 8 + ee] = f2bf(Wl[k * 64 + col]);
                }
            }
        }
        return;
    }
    __shared__ int lcnt[256];
    __shared__ int lcur[256];
    if (t < 256) lcnt[t] = 0;
    __syncthreads();
    int base = blockIdx.x * CHUNK;
    int lim  = e - base; if (lim > CHUNK) lim = CHUNK;
    for (int j = t; j < lim; j += 1024)
        atomicAdd(&lcnt[dst[base + j] >> BSHIFT], 1);
    if (blockIdx.x == 0 && t >= 512 && t < 576)
        xws[(size_t)n * 64 + (t - 512)] = 0;               // sentinel row
    __syncthreads();
    if (t < nbk) {
        int c = lcnt[t];
        lcur[t] = (c > 0) ? (t * cap + atomicAdd(&gcur[t], c)) : 0;
    }
    __syncthreads();
    for (int j = t; j < lim; j += 1024) {
        int i = base + j;
        int d = dst[i];
        int pos = atomicAdd(&lcur[d >> BSHIFT], 1);
        ebuf[pos] = (unsigned)src[i] | ((unsigned)(d & (BSZ - 1)) << 23);
    }
}

// ---------------------------------------------------------------------------
// fillmerge (r11 structure): per-bucket degree count -> dinv + rowinfo,
// CSR space via one global atomic per block, fill CSR with LDS cursors,
// pad with sentinel n. Bucket b's edges live at [b*cap, b*cap + gcur[b]).
// ---------------------------------------------------------------------------
__global__ __launch_bounds__(1024) void fillmerge_kernel(const unsigned* __restrict__ ebuf,
                                                         const int* __restrict__ gcur,
                                                         int* __restrict__ galloc,
                                                         int2* __restrict__ rowinfo,
                                                         float* __restrict__ dinv,
                                                         int* __restrict__ csr,
                                                         int cap, int nbk, int n) {
    __shared__ int lc[BSZ];
    __shared__ int pref[BSZ];
    __shared__ int cur[BSZ];
    __shared__ int basesh;
    int t = threadIdx.x;
    int b = blockIdx.x;
    if (t < BSZ) lc[t] = 0;
    __syncthreads();
    int bs = b * cap;
    int be = bs + gcur[b];
    for (int i = bs + t; i < be; i += 1024)
        atomicAdd(&lc[ebuf[i] >> 23], 1);
    __syncthreads();
    int v = (b << BSHIFT) + t;
    int deg = 0, pd = 0;
    if (t < BSZ && v < n) {
        deg = lc[t];
        pd  = (deg + 7) & ~7;
    }
    if (t < BSZ) pref[t] = pd;
    __syncthreads();
    for (int s = 1; s < BSZ; s <<= 1) {
        int x = (t < BSZ && t >= s) ? pref[t - s] : 0;
        __syncthreads();
        if (t < BSZ) pref[t] += x;
        __syncthreads();
    }
    if (t == 0) basesh = atomicAdd(galloc, pref[BSZ - 1]);
    __syncthreads();
    int base = basesh;
    int start = 0;
    if (t < BSZ) {
        start  = base + pref[t] - pd;
        cur[t] = start;
        if (v < n) {
            rowinfo[v] = make_int2(start, pd);
            dinv[v]    = rsqrtf((float)deg + 1.0f);
        }
    }
    __syncthreads();
    for (int i = bs + t; i < be; i += 1024) {
        unsigned ev = ebuf[i];
        int slot = atomicAdd(&cur[ev >> 23], 1);
        csr[slot] = (int)(ev & SRCMASK);
    }
    __syncthreads();
    if (t < BSZ && v < n) {
        int endp = start + pd;
        for (int s2 = cur[t]; s2 < endp; ++s2) csr[s2] = n;   // pad sentinels
    }
}

// ---------------------------------------------------------------------------
// MFMA gemm: xws = (Xin @ W) * dinv[row], bf16 out. (r11, unchanged)
// A/B packed with the same k-bijection (lg*8+e+32f) -> sum over k is exact.
// C/D layout (verified m89): col = lane&15, row = (lane>>4)*4 + reg.
// ---------------------------------------------------------------------------
template<int XF32>
__global__ __launch_bounds__(256) void gemm_mfma(const float* __restrict__ Xf,
                                                 const ushort_t* __restrict__ Xh,
                                                 const ushort_t* __restrict__ wfrag,
                                                 const float* __restrict__ dinv,
                                                 ushort_t* __restrict__ xws, int n) {
    int lane = threadIdx.x & 63;
    int wv   = threadIdx.x >> 6;
    int lg   = lane >> 4;
    int li   = lane & 15;

    short8 bfr[8];
    const short8* wp = (const short8*)wfrag;
    #pragma unroll
    for (int f8 = 0; f8 < 8; ++f8) bfr[f8] = wp[f8 * 64 + lane];

    int row0 = (blockIdx.x * 4 + wv) * 64;

    #pragma unroll 1
    for (int it = 0; it < 4; ++it) {
        int rbase = row0 + it * 16;
        if (rbase >= n) break;
        int r = rbase + li;

        short8 afr[2];
        if (XF32) {
            #pragma unroll
            for (int f = 0; f < 2; ++f) {
                const float* p = Xf + (size_t)r * 64 + lg * 8 + 32 * f;
                float4 c0 = *(const float4*)(p);
                float4 c1 = *(const float4*)(p + 4);
                short8 a;
                a[0] = (short)f2bf(c0.x); a[1] = (short)f2bf(c0.y);
                a[2] = (short)f2bf(c0.z); a[3] = (short)f2bf(c0.w);
                a[4] = (short)f2bf(c1.x); a[5] = (short)f2bf(c1.y);
                a[6] = (short)f2bf(c1.z); a[7] = (short)f2bf(c1.w);
                afr[f] = a;
            }
        } else {
            const ushort_t* p = Xh + (size_t)r * 64 + lg * 8;
            afr[0] = *(const short8*)(p);
            afr[1] = *(const short8*)(p + 32);
        }

        float dv[4];
        #pragma unroll
        for (int reg = 0; reg < 4; ++reg) dv[reg] = dinv[rbase + lg * 4 + reg];

        #pragma unroll
        for (int cg = 0; cg < 4; ++cg) {
            f32x4 acc = {0.f, 0.f, 0.f, 0.f};
            acc = __builtin_amdgcn_mfma_f32_16x16x32_bf16(afr[0], bfr[cg * 2 + 0], acc, 0, 0, 0);
            acc = __builtin_amdgcn_mfma_f32_16x16x32_bf16(afr[1], bfr[cg * 2 + 1], acc, 0, 0, 0);
            #pragma unroll
            for (int reg = 0; reg < 4; ++reg) {
                int rr = rbase + lg * 4 + reg;
                xws[(size_t)rr * 64 + cg * 16 + li] = f2bf(acc[reg] * dv[reg]);
            }
        }
    }
}

// ---------------------------------------------------------------------------
// pull aggregation (r11, unchanged): two nodes per wave, 8+8 interleave,
// register accumulation, leakyReLU + residual fused. FINAL=1 fuses the
// weighted running-sum output and skips the bf16 write.
// ---------------------------------------------------------------------------
template<int XF32, int FINAL>
__global__ __launch_bounds__(256) void agg_kernel(
        const ushort_t* __restrict__ xws,
        const int2* __restrict__ rowinfo,
        const int* __restrict__ csr,
        const float* __restrict__ dinv,
        const float* __restrict__ bias,
        const float* __restrict__ xinf,    // f32 input (layer 0)
        const ushort_t* __restrict__ xinh, // bf16 input (layers >0)
        ushort_t* __restrict__ xout,       // bf16 layer output (FINAL=0)
        const float* __restrict__ Xres,    // X (FINAL=1)
        const ushort_t* __restrict__ x1res,// x1 (FINAL=1)
        float* __restrict__ outf,          // final f32 out (FINAL=1)
        int n) {
    int tid = threadIdx.x;
    int c   = tid & 63;
    int w   = blockIdx.x * 4 + (tid >> 6);
    int v0  = w * 2;
    if (v0 >= n) return;
    int  v1   = v0 + 1;
    bool has1 = (v1 < n);
    int  v1c  = has1 ? v1 : v0;

    int2 ri0 = rowinfo[v0];
    int2 ri1 = rowinfo[v1c];
    int b0 = ri0.x, len0 = ri0.y;
    int b1 = ri1.x, len1 = has1 ? ri1.y : 0;

    size_t vo0 = (size_t)v0  * 64 + c;
    size_t vo1 = (size_t)v1c * 64 + c;
    float acc0 = bf2f(xws[vo0]);     // self term (pre-scaled by dinv)
    float acc1 = bf2f(xws[vo1]);

    int mxlen = len0 > len1 ? len0 : len1;
    for (int off = 0; off < mxlen; off += 64) {
        int r0 = len0 - off;
        int r1 = len1 - off;
        int ce0 = (c < r0) ? csr[b0 + off + c] : n;
        int ce1 = (c < r1) ? csr[b1 + off + c] : n;
        int m0 = r0 < 64 ? r0 : 64;           // multiple of 8 (or <=0)
        int m1 = r1 < 64 ? r1 : 64;
        int mx = m0 > m1 ? m0 : m1;
        for (int j0 = 0; j0 < mx; j0 += 8) {
            float g0[8], g1[8];
            bool p0 = j0 < m0, p1 = j0 < m1;
            if (p0) {
                #pragma unroll
                for (int j = 0; j < 8; ++j) {
                    int s = __builtin_amdgcn_readlane(ce0, j0 + j);
                    g0[j] = bf2f(xws[(size_t)(unsigned)s * 64 + c]);
                }
            }
            if (p1) {
                #pragma unroll
                for (int j = 0; j < 8; ++j) {
                    int s = __builtin_amdgcn_readlane(ce1, j0 + j);
                    g1[j] = bf2f(xws[(size_t)(unsigned)s * 64 + c]);
                }
            }
            if (p0) {
                #pragma unroll
                for (int j = 0; j < 8; ++j) acc0 += g0[j];
            }
            if (p1) {
                #pragma unroll
                for (int j = 0; j < 8; ++j) acc1 += g1[j];
            }
        }
    }

    {
        float dv0 = dinv[v0];
        float t0  = bias[c] + dv0 * acc0;
        float a0  = t0 >= 0.f ? t0 : NEG_SLOPE * t0;
        float xi0 = XF32 ? xinf[vo0] : bf2f(xinh[vo0]);
        float xn0 = a0 + xi0;
        if (FINAL) {
            outf[vo0] = Xres[vo0] + 0.5f * bf2f(x1res[vo0])
                        + (1.f / 3.f) * xi0 + 0.25f * xn0;
        } else {
            xout[vo0] = f2bf(xn0);
        }
    }
    if (has1) {
        float dv1 = dinv[v1];
        float t1  = bias[c] + dv1 * acc1;
        float a1  = t1 >= 0.f ? t1 : NEG_SLOPE * t1;
        float xi1 = XF32 ? xinf[vo1] : bf2f(xinh[vo1]);
        float xn1 = a1 + xi1;
        if (FINAL) {
            outf[vo1] = Xres[vo1] + 0.5f * bf2f(x1res[vo1])
                        + (1.f / 3.f) * xi1 + 0.25f * xn1;
        } else {
            xout[vo1] = f2bf(xn1);
        }
    }
}

extern "C" void kernel_launch(void* const* d_in, const int* in_sizes, int n_in,
                              void* d_out, int out_size, void* d_ws, size_t ws_size,
                              hipStream_t stream) {
    const float* X   = (const float*)d_in[0];
    const int*   adj = (const int*)d_in[1];
    const float* W   = (const float*)d_in[2];
    const float* b   = (const float*)d_in[3];
    float* out = (float*)d_out;

    const int nd = in_sizes[0];          // N * 64
    const int n  = nd >> 6;              // N
    const int e  = in_sizes[1] / 2;      // E
    const int L  = in_sizes[3] / 64;     // layers (3)

    const int* src = adj;
    const int* dst = adj + e;

    const int nbk = (n + BSZ - 1) >> BSHIFT;             // ~196
    const int nch = (e + CHUNK - 1) / CHUNK;             // ~77
    const int cap = (e + nbk - 1) / nbk + 1024;          // per-bucket region
    const int csr_len = e + 8 * n + 64;

    // workspace layout
    unsigned* ebuf   = (unsigned*)d_ws;                  // nbk * cap u32
    int*      csr    = (int*)(ebuf + (size_t)nbk * cap); // csr_len
    int*      gcur   = csr + csr_len;                    // nbk (+ galloc)
    int*      galloc = gcur + 256;                       // 4
    ushort_t* wfrag  = (ushort_t*)(galloc + 4);          // 3 * 4096 bf16 (24KB)
    int2*     rowinfo= (int2*)(wfrag + 3 * 4096);        // n int2
    float*    dinv   = (float*)(rowinfo + n);            // n
    size_t    off    = ((size_t)(n + 3) & ~(size_t)3);
    ushort_t* xws    = (ushort_t*)(dinv + off);          // nd + 64
    ushort_t* x1     = xws + (size_t)nd + 64;            // nd
    ushort_t* x2     = x1  + (size_t)nd;                 // nd

    // ---- preprocessing: zero cursors, merged hist+alloc+reorder, fill ----
    hipMemsetAsync(gcur, 0, (size_t)(256 + 4) * sizeof(int), stream);
    reorder2_kernel<<<nch + L, 1024, 0, stream>>>(src, dst, gcur, ebuf,
                                                  W, wfrag, xws,
                                                  e, nbk, nch, cap, n, L);
    fillmerge_kernel<<<nbk, 1024, 0, stream>>>(ebuf, gcur, galloc, rowinfo, dinv,
                                               csr, cap, nbk, n);

    // ---- layers ----
    int gemm_blocks = (n + 255) / 256;   // 4 waves x 64 rows per block
    int agg_blocks  = (n + 7) / 8;       // 2 nodes/wave, 4 waves/block
    // layer 0 (f32 X in, bf16 x1 out)
    gemm_mfma<1><<<gemm_blocks, 256, 0, stream>>>(X, nullptr, wfrag, dinv, xws, n);
    agg_kernel<1, 0><<<agg_blocks, 256, 0, stream>>>(xws, rowinfo, csr, dinv, b,
                                                     X, nullptr, x1,
                                                     nullptr, nullptr, nullptr, n);
    // layer 1
    gemm_mfma<0><<<gemm_blocks, 256, 0, stream>>>(nullptr, x1, wfrag + 4096, dinv, xws, n);
    agg_kernel<0, 0><<<agg_blocks, 256, 0, stream>>>(xws, rowinfo, csr, dinv, b + 64,
                                                     nullptr, x1, x2,
                                                     nullptr, nullptr, nullptr, n);
    // layer 2 (fused final: out = X + x1/2 + x2/3 + xn3/4)
    gemm_mfma<0><<<gemm_blocks, 256, 0, stream>>>(nullptr, x2, wfrag + 8192, dinv, xws, n);
    agg_kernel<0, 1><<<agg_blocks, 256, 0, stream>>>(xws, rowinfo, csr, dinv, b + 128,
                                                     nullptr, x2, nullptr,
                                                     X, x1, out, n);
}